// Round 8
// baseline (361.993 us; speedup 1.0000x reference)
//
#include <hip/hip_runtime.h>
#include <math.h>

#define RDIM 192
#define FDIM 28
#define HPTS 4              // points per 16-lane group
#define PPB  64             // 16 groups x 4 points

// SH constants (match reference)
#define SH_C0  0.28209479177387814f
#define SH_C1  0.4886025119029199f
#define SH_C2  0.5462742152960396f
#define SH_C20 0.15769578262626154f
#define SH_C22 0.2731371076480198f

__global__ __launch_bounds__(256)
void plenoxel_fwd(const float* __restrict__ points,
                  const float* __restrict__ voxels,
                  float* __restrict__ out_rgb,    // N*3
                  float* __restrict__ out_sigma,  // N
                  int N)
{
    __shared__ float feats[PPB][FDIM];   // 7 KB
    __shared__ float4 plds[PPB];         // 1 KB

    const int tid = threadIdx.x;
    const int G   = tid >> 4;     // 16-lane group 0..15
    const int l   = tid & 15;     // lane in group
    const int pbase = blockIdx.x * PPB;
    const float4* __restrict__ src = (const float4*)voxels;

    const float A   = (RDIM - 1) / 8.0f;   // 23.875
    const float B   = (RDIM - 1) * 0.5f;   // 95.5
    const float RM1 = (float)(RDIM - 1);

    // ---- setup per point h: 4 segment bases (float4 idx), wzy weights, gx/fx
#define POINT_SETUP(h)                                                        \
    const int p##h  = pbase + G + 16 * h;                                     \
    const int cp##h = min(p##h, N - 1);                                       \
    const float px##h = points[3 * cp##h + 0];                                \
    const float py##h = points[3 * cp##h + 1];                                \
    const float pz##h = points[3 * cp##h + 2];                                \
    if (l == 0) plds[G + 16 * h] = make_float4(px##h, py##h, pz##h, 0.0f);    \
    float cx##h = fminf(fmaxf(px##h * A + B, 0.0f), RM1);                     \
    float cy##h = fminf(fmaxf(py##h * A + B, 0.0f), RM1);                     \
    float cz##h = fminf(fmaxf(pz##h * A + B, 0.0f), RM1);                     \
    float fcx##h = floorf(cx##h), fcy##h = floorf(cy##h), fcz##h = floorf(cz##h); \
    float fx##h = cx##h - fcx##h, fy##h = cy##h - fcy##h, fz##h = cz##h - fcz##h; \
    int x0##h = (int)fcx##h, y0##h = (int)fcy##h, z0##h = (int)fcz##h;        \
    int x1##h = min(x0##h + 1, RDIM - 1);                                     \
    int y1##h = min(y0##h + 1, RDIM - 1);                                     \
    int z1##h = min(z0##h + 1, RDIM - 1);                                     \
    float gx##h = 1.0f - fx##h, gy##h = 1.0f - fy##h, gz##h = 1.0f - fz##h;   \
    float wzy##h##0 = gz##h * gy##h;                                          \
    float wzy##h##1 = gz##h * fy##h;                                          \
    float wzy##h##2 = fz##h * gy##h;                                          \
    float wzy##h##3 = fz##h * fy##h;                                          \
    /* per-lane x offset within the 224B pair; clamp-safe */                  \
    int xo##h; {                                                              \
        if (l < 7)       xo##h = l;                                           \
        else if (l < 14) xo##h = (x1##h > x0##h) ? l : l - 7;                 \
        else             xo##h = 0;                                           \
    }                                                                         \
    int a##h##0 = ((z0##h * RDIM + y0##h) * RDIM + x0##h) * 7 + xo##h;        \
    int a##h##1 = ((z0##h * RDIM + y1##h) * RDIM + x0##h) * 7 + xo##h;        \
    int a##h##2 = ((z1##h * RDIM + y0##h) * RDIM + x0##h) * 7 + xo##h;        \
    int a##h##3 = ((z1##h * RDIM + y1##h) * RDIM + x0##h) * 7 + xo##h;

    POINT_SETUP(0)
    POINT_SETUP(1)
    POINT_SETUP(2)
    POINT_SETUP(3)
#undef POINT_SETUP

    // ---- issue all 16 independent 224B-pair loads ----
    float4 v00 = src[a00]; float4 v01 = src[a01];
    float4 v02 = src[a02]; float4 v03 = src[a03];
    float4 v10 = src[a10]; float4 v11 = src[a11];
    float4 v12 = src[a12]; float4 v13 = src[a13];
    float4 v20 = src[a20]; float4 v21 = src[a21];
    float4 v22 = src[a22]; float4 v23 = src[a23];
    float4 v30 = src[a30]; float4 v31 = src[a31];
    float4 v32 = src[a32]; float4 v33 = src[a33];

    // ---- per-point: t = (sum_s wzy_s * v_s) * wx ; fold x1-half onto x0-half
#define REDUCE_STORE(h, V0, V1, V2, V3)                                       \
    {                                                                         \
        float wx = (l < 7) ? gx##h : fx##h;                                   \
        float4 t;                                                             \
        t.x = (wzy##h##0 * V0.x + wzy##h##1 * V1.x                            \
             + wzy##h##2 * V2.x + wzy##h##3 * V3.x) * wx;                     \
        t.y = (wzy##h##0 * V0.y + wzy##h##1 * V1.y                            \
             + wzy##h##2 * V2.y + wzy##h##3 * V3.y) * wx;                     \
        t.z = (wzy##h##0 * V0.z + wzy##h##1 * V1.z                            \
             + wzy##h##2 * V2.z + wzy##h##3 * V3.z) * wx;                     \
        t.w = (wzy##h##0 * V0.w + wzy##h##1 * V1.w                            \
             + wzy##h##2 * V2.w + wzy##h##3 * V3.w) * wx;                     \
        float sx = __shfl_down(t.x, 7, 16);                                   \
        float sy = __shfl_down(t.y, 7, 16);                                   \
        float sz = __shfl_down(t.z, 7, 16);                                   \
        float sw = __shfl_down(t.w, 7, 16);                                   \
        if (l < 7) {                                                          \
            float4 r = make_float4(t.x + sx, t.y + sy, t.z + sz, t.w + sw);   \
            *(float4*)&feats[G + 16 * h][4 * l] = r;                          \
        }                                                                     \
    }

    REDUCE_STORE(0, v00, v01, v02, v03)
    REDUCE_STORE(1, v10, v11, v12, v13)
    REDUCE_STORE(2, v20, v21, v22, v23)
    REDUCE_STORE(3, v30, v31, v32, v33)
#undef REDUCE_STORE

    __syncthreads();

    // ---- epilogue: one thread per point (64 of 256) ----
    if (tid < PPB) {
        int p2 = pbase + tid;
        if (p2 < N) {
            float4 pt = plds[tid];
            float px = pt.x, py = pt.y, pz = pt.z;

            float inv = rsqrtf(px * px + py * py + pz * pz);
            float dx = px * inv, dy = py * inv, dz = pz * inv;

            float basis[9];
            basis[0] = SH_C0;
            basis[1] = SH_C1 * dy;
            basis[2] = SH_C1 * dz;
            basis[3] = SH_C1 * dx;
            basis[4] = SH_C2 * dx * dy;
            basis[5] = SH_C2 * dy * dz;
            basis[6] = SH_C20 * (3.0f * dz * dz - 1.0f);
            basis[7] = SH_C2 * dx * dz;
            basis[8] = SH_C22 * (dx * dx - dy * dy);

#pragma unroll
            for (int c = 0; c < 3; ++c) {
                float s = 0.0f;
#pragma unroll
                for (int j = 0; j < 9; ++j) {
                    s += feats[tid][1 + 9 * c + j] * basis[j];
                }
                float r = 1.0f / (1.0f + expf(-s));
                __builtin_nontemporal_store(r, &out_rgb[3 * p2 + c]);
            }

            float x = feats[tid][0];
            float sig = fmaxf(x, 0.0f) + log1pf(expf(-fabsf(x)));
            __builtin_nontemporal_store(sig, &out_sigma[p2]);
        }
    }
}

extern "C" void kernel_launch(void* const* d_in, const int* in_sizes, int n_in,
                              void* d_out, int out_size, void* d_ws, size_t ws_size,
                              hipStream_t stream) {
    const float* points = (const float*)d_in[0];
    const float* voxels = (const float*)d_in[1];
    int N = in_sizes[0] / 3;

    float* out_rgb = (float*)d_out;              // N*3
    float* out_sigma = out_rgb + (size_t)3 * N;  // N

    int blocks = (N + PPB - 1) / PPB;
    plenoxel_fwd<<<blocks, 256, 0, stream>>>(points, voxels, out_rgb, out_sigma, N);
}

// Round 10
// 354.712 us; speedup vs baseline: 1.0205x; 1.0205x over previous
//
#include <hip/hip_runtime.h>
#include <math.h>

#define RDIM 192
#define FDIM 28
#define PPB 64   // points per 256-thread block: 2 per 8-lane group

// SH constants (match reference)
#define SH_C0  0.28209479177387814f
#define SH_C1  0.4886025119029199f
#define SH_C2  0.5462742152960396f
#define SH_C20 0.15769578262626154f
#define SH_C22 0.2731371076480198f

// clang native vector type: __builtin_nontemporal_load accepts this
typedef float vf4 __attribute__((ext_vector_type(4)));

__global__ __launch_bounds__(256)
void plenoxel_fwd(const float* __restrict__ points,
                  const float* __restrict__ voxels,
                  float* __restrict__ out_rgb,    // N*3
                  float* __restrict__ out_sigma,  // N
                  int N)
{
    __shared__ float feats[PPB][FDIM];   // 7 KB
    __shared__ float4 plds[PPB];         // 1 KB (x,y,z for epilogue)

    const int tid   = threadIdx.x;
    const int group = tid >> 3;   // 0..31
    const int f     = tid & 7;    // 0..7 (lane 7 idle for loads)
    const int pbase = blockIdx.x * PPB;
    const vf4* __restrict__ src = (const vf4*)voxels;

    const float A   = (RDIM - 1) / 8.0f;   // 23.875
    const float B   = (RDIM - 1) * 0.5f;   // 95.5
    const float RM1 = (float)(RDIM - 1);

    if (f < 7) {
        // ---- per-point setup macro: weights w<h>_*, float4-base a<h>_*,
        //      hot<h> = point in the L3-resident +-2sigma core ----
#define POINT_SETUP(h, PIDX)                                                  \
        const int p##h  = (PIDX);                                             \
        const int cp##h = min(p##h, N - 1);                                   \
        const float px##h = points[3 * cp##h + 0];                            \
        const float py##h = points[3 * cp##h + 1];                            \
        const float pz##h = points[3 * cp##h + 2];                            \
        if (f == 0) plds[group + 32 * h] =                                    \
            make_float4(px##h, py##h, pz##h, 0.0f);                           \
        const bool hot##h =                                                   \
            fmaxf(fabsf(px##h), fmaxf(fabsf(py##h), fabsf(pz##h))) <= 2.0f;   \
        float cx##h = fminf(fmaxf(px##h * A + B, 0.0f), RM1);                 \
        float cy##h = fminf(fmaxf(py##h * A + B, 0.0f), RM1);                 \
        float cz##h = fminf(fmaxf(pz##h * A + B, 0.0f), RM1);                 \
        float fcx##h = floorf(cx##h), fcy##h = floorf(cy##h),                 \
              fcz##h = floorf(cz##h);                                         \
        float fx##h = cx##h - fcx##h, fy##h = cy##h - fcy##h,                 \
              fz##h = cz##h - fcz##h;                                         \
        int x0##h = (int)fcx##h, y0##h = (int)fcy##h, z0##h = (int)fcz##h;    \
        int x1##h = min(x0##h + 1, RDIM - 1);                                 \
        int y1##h = min(y0##h + 1, RDIM - 1);                                 \
        int z1##h = min(z0##h + 1, RDIM - 1);                                 \
        float gx##h = 1.0f - fx##h, gy##h = 1.0f - fy##h,                     \
              gz##h = 1.0f - fz##h;                                           \
        float w##h##0 = gz##h * gy##h * gx##h;                                \
        float w##h##1 = gz##h * gy##h * fx##h;                                \
        float w##h##2 = gz##h * fy##h * gx##h;                                \
        float w##h##3 = gz##h * fy##h * fx##h;                                \
        float w##h##4 = fz##h * gy##h * gx##h;                                \
        float w##h##5 = fz##h * gy##h * fx##h;                                \
        float w##h##6 = fz##h * fy##h * gx##h;                                \
        float w##h##7 = fz##h * fy##h * fx##h;                                \
        int a##h##0 = ((((z0##h * RDIM + y0##h) * RDIM + x0##h) * FDIM) >> 2) + f; \
        int a##h##1 = ((((z0##h * RDIM + y0##h) * RDIM + x1##h) * FDIM) >> 2) + f; \
        int a##h##2 = ((((z0##h * RDIM + y1##h) * RDIM + x0##h) * FDIM) >> 2) + f; \
        int a##h##3 = ((((z0##h * RDIM + y1##h) * RDIM + x1##h) * FDIM) >> 2) + f; \
        int a##h##4 = ((((z1##h * RDIM + y0##h) * RDIM + x0##h) * FDIM) >> 2) + f; \
        int a##h##5 = ((((z1##h * RDIM + y0##h) * RDIM + x1##h) * FDIM) >> 2) + f; \
        int a##h##6 = ((((z1##h * RDIM + y1##h) * RDIM + x0##h) * FDIM) >> 2) + f; \
        int a##h##7 = ((((z1##h * RDIM + y1##h) * RDIM + x1##h) * FDIM) >> 2) + f;

        POINT_SETUP(0, pbase + group)
        POINT_SETUP(1, pbase + group + 32)
#undef POINT_SETUP

        // ---- issue all 16 independent 16B loads.
        //      Hot (core) points: normal loads (L3-allocate).
        //      Tail points: non-temporal (stream past L3, protect core). ----
        vf4 v00, v01, v02, v03, v04, v05, v06, v07;
        vf4 v10, v11, v12, v13, v14, v15, v16, v17;

        if (hot0) {
            v00 = src[a00]; v01 = src[a01]; v02 = src[a02]; v03 = src[a03];
            v04 = src[a04]; v05 = src[a05]; v06 = src[a06]; v07 = src[a07];
        } else {
            v00 = __builtin_nontemporal_load(&src[a00]);
            v01 = __builtin_nontemporal_load(&src[a01]);
            v02 = __builtin_nontemporal_load(&src[a02]);
            v03 = __builtin_nontemporal_load(&src[a03]);
            v04 = __builtin_nontemporal_load(&src[a04]);
            v05 = __builtin_nontemporal_load(&src[a05]);
            v06 = __builtin_nontemporal_load(&src[a06]);
            v07 = __builtin_nontemporal_load(&src[a07]);
        }
        if (hot1) {
            v10 = src[a10]; v11 = src[a11]; v12 = src[a12]; v13 = src[a13];
            v14 = src[a14]; v15 = src[a15]; v16 = src[a16]; v17 = src[a17];
        } else {
            v10 = __builtin_nontemporal_load(&src[a10]);
            v11 = __builtin_nontemporal_load(&src[a11]);
            v12 = __builtin_nontemporal_load(&src[a12]);
            v13 = __builtin_nontemporal_load(&src[a13]);
            v14 = __builtin_nontemporal_load(&src[a14]);
            v15 = __builtin_nontemporal_load(&src[a15]);
            v16 = __builtin_nontemporal_load(&src[a16]);
            v17 = __builtin_nontemporal_load(&src[a17]);
        }

        // ---- accumulate & stash ----
#define ACC_STORE(h, V0, V1, V2, V3, V4, V5, V6, V7, ROW)                     \
        {                                                                     \
            float4 acc;                                                       \
            acc.x = w##h##0 * V0.x + w##h##1 * V1.x + w##h##2 * V2.x          \
                  + w##h##3 * V3.x + w##h##4 * V4.x + w##h##5 * V5.x          \
                  + w##h##6 * V6.x + w##h##7 * V7.x;                          \
            acc.y = w##h##0 * V0.y + w##h##1 * V1.y + w##h##2 * V2.y          \
                  + w##h##3 * V3.y + w##h##4 * V4.y + w##h##5 * V5.y          \
                  + w##h##6 * V6.y + w##h##7 * V7.y;                          \
            acc.z = w##h##0 * V0.z + w##h##1 * V1.z + w##h##2 * V2.z          \
                  + w##h##3 * V3.z + w##h##4 * V4.z + w##h##5 * V5.z          \
                  + w##h##6 * V6.z + w##h##7 * V7.z;                          \
            acc.w = w##h##0 * V0.w + w##h##1 * V1.w + w##h##2 * V2.w          \
                  + w##h##3 * V3.w + w##h##4 * V4.w + w##h##5 * V5.w          \
                  + w##h##6 * V6.w + w##h##7 * V7.w;                          \
            *(float4*)&feats[ROW][4 * f] = acc;                               \
        }

        ACC_STORE(0, v00, v01, v02, v03, v04, v05, v06, v07, group)
        ACC_STORE(1, v10, v11, v12, v13, v14, v15, v16, v17, group + 32)
#undef ACC_STORE
    }

    __syncthreads();

    // ---- epilogue: one thread per point (64 of 256) ----
    if (tid < PPB) {
        int p2 = pbase + tid;
        if (p2 < N) {
            float4 pt = plds[tid];
            float px = pt.x, py = pt.y, pz = pt.z;

            float inv = rsqrtf(px * px + py * py + pz * pz);
            float dx = px * inv, dy = py * inv, dz = pz * inv;

            float basis[9];
            basis[0] = SH_C0;
            basis[1] = SH_C1 * dy;
            basis[2] = SH_C1 * dz;
            basis[3] = SH_C1 * dx;
            basis[4] = SH_C2 * dx * dy;
            basis[5] = SH_C2 * dy * dz;
            basis[6] = SH_C20 * (3.0f * dz * dz - 1.0f);
            basis[7] = SH_C2 * dx * dz;
            basis[8] = SH_C22 * (dx * dx - dy * dy);

#pragma unroll
            for (int c = 0; c < 3; ++c) {
                float s = 0.0f;
#pragma unroll
                for (int j = 0; j < 9; ++j) {
                    s += feats[tid][1 + 9 * c + j] * basis[j];
                }
                float r = 1.0f / (1.0f + expf(-s));
                __builtin_nontemporal_store(r, &out_rgb[3 * p2 + c]);
            }

            float x = feats[tid][0];
            float sig = fmaxf(x, 0.0f) + log1pf(expf(-fabsf(x)));
            __builtin_nontemporal_store(sig, &out_sigma[p2]);
        }
    }
}

extern "C" void kernel_launch(void* const* d_in, const int* in_sizes, int n_in,
                              void* d_out, int out_size, void* d_ws, size_t ws_size,
                              hipStream_t stream) {
    const float* points = (const float*)d_in[0];
    const float* voxels = (const float*)d_in[1];
    int N = in_sizes[0] / 3;

    float* out_rgb = (float*)d_out;              // N*3
    float* out_sigma = out_rgb + (size_t)3 * N;  // N

    int blocks = (N + PPB - 1) / PPB;
    plenoxel_fwd<<<blocks, 256, 0, stream>>>(points, voxels, out_rgb, out_sigma, N);
}